// Round 1
// baseline (444.572 us; speedup 1.0000x reference)
//
#include <hip/hip_runtime.h>

// Shift: out[b,c,h,w] = x[b,c, clamp(h + trunc(ypos[h]*stride), 0, H-1),
//                              clamp(w + trunc(xpos[w]*stride), 0, W-1)]
// B=16, C=64, H=256, W=256, fp32. Pure memory-bound gather (row-shift + ~identity col-shift).

constexpr int Bc = 16;
constexpr int Cc = 64;
constexpr int Hc = 256;
constexpr int Wc = 256;

__global__ __launch_bounds__(256) void shift_kernel(
    const float* __restrict__ x,
    const float* __restrict__ xpos,
    const float* __restrict__ ypos,
    const int* __restrict__ stride_p,
    float* __restrict__ out)
{
    const int stride = *stride_p;

    // Each thread handles 4 consecutive w elements. 64 threads per row (1 wave/row... well,
    // 64 lanes cover one row of 256 elems; a 256-thread block covers 4 rows).
    const long long tid = (long long)blockIdx.x * blockDim.x + threadIdx.x;
    const int lane_in_row = (int)(tid & (Wc / 4 - 1));       // 0..63
    const int w0 = lane_in_row * 4;
    const long long rowIdx = tid >> 6;                        // b*C*H + c*H + h
    const int h = (int)(rowIdx & (Hc - 1));

    // Row shift: trunc toward zero matches Python int()
    int sh = h + (int)(ypos[h] * (float)stride);
    sh = min(max(sh, 0), Hc - 1);

    const long long planeIdx = rowIdx >> 8;                   // b*C + c
    const float* __restrict__ src = x + (planeIdx * Hc + sh) * (long long)Wc;

    float r[4];
#pragma unroll
    for (int i = 0; i < 4; ++i) {
        const int w = w0 + i;
        int sw = w + (int)(xpos[w] * (float)stride);
        sw = min(max(sw, 0), Wc - 1);
        r[i] = src[sw];
    }

    float4 v = make_float4(r[0], r[1], r[2], r[3]);
    *reinterpret_cast<float4*>(out + rowIdx * (long long)Wc + w0) = v;
}

extern "C" void kernel_launch(void* const* d_in, const int* in_sizes, int n_in,
                              void* d_out, int out_size, void* d_ws, size_t ws_size,
                              hipStream_t stream)
{
    const float* x     = (const float*)d_in[0];
    const float* xpos  = (const float*)d_in[1];
    const float* ypos  = (const float*)d_in[2];
    const int* stride  = (const int*)d_in[3];
    float* out         = (float*)d_out;

    const long long total_threads = (long long)Bc * Cc * Hc * (Wc / 4);  // 16.8M
    const int block = 256;
    const long long grid = total_threads / block;                        // 65536

    shift_kernel<<<(int)grid, block, 0, stream>>>(x, xpos, ypos, stride, out);
}

// Round 2
// 419.150 us; speedup vs baseline: 1.0607x; 1.0607x over previous
//
#include <hip/hip_runtime.h>

// Shift: out[b,c,h,w] = x[b,c, clamp(h + trunc(ypos[h]*stride), 0, H-1),
//                              clamp(w + trunc(xpos[w]*stride), 0, W-1)]
// B=16, C=64, H=256, W=256, fp32.
//
// sh is row-uniform -> stage source rows into LDS with fully-coalesced float4
// reads; do the per-element w-gather out of LDS (conflict-free: consecutive
// lanes hit consecutive addresses when xpos ~ 0).

constexpr int Bc = 16;
constexpr int Cc = 64;
constexpr int Hc = 256;
constexpr int Wc = 256;
constexpr int ROWS = 16;   // output rows per block; LDS = 16*256*4 = 16 KiB

__global__ __launch_bounds__(256) void shift_kernel(
    const float* __restrict__ x,
    const float* __restrict__ xpos,
    const float* __restrict__ ypos,
    const int* __restrict__ stride_p,
    float* __restrict__ out)
{
    __shared__ float lds[ROWS][Wc];

    const int stride = *stride_p;
    const int t  = threadIdx.x;
    const int wv = t >> 6;                 // wave id 0..3
    const int ln = t & 63;                 // lane 0..63

    const int plane = blockIdx.x >> 4;             // (b*C + c), 16 blocks per plane
    const int h0    = (blockIdx.x & 15) * ROWS;

    const float* __restrict__ src_plane = x + (long long)plane * Hc * Wc;

    // ---- Phase 1: stage 16 source rows, coalesced float4 (1 KiB/row/wave) ----
    // iter k, wave wv handles LDS row r = wv + 4k; lane ln loads cols 4ln..4ln+3.
#pragma unroll
    for (int k = 0; k < 4; ++k) {
        const int r = wv + 4 * k;
        const int h = h0 + r;
        int sh = h + (int)(ypos[h] * (float)stride);   // row-uniform
        sh = min(max(sh, 0), Hc - 1);
        const float4 v = *reinterpret_cast<const float4*>(src_plane + sh * Wc + ln * 4);
        *reinterpret_cast<float4*>(&lds[r][ln * 4]) = v;
    }

    __syncthreads();

    // ---- Phase 2: per-column gather from LDS, contiguous dword stores ----
    int sw = t + (int)(xpos[t] * (float)stride);
    sw = min(max(sw, 0), Wc - 1);

    float* __restrict__ dst = out + ((long long)plane * Hc + h0) * Wc + t;
#pragma unroll
    for (int r = 0; r < ROWS; ++r) {
        dst[r * Wc] = lds[r][sw];
    }
}

extern "C" void kernel_launch(void* const* d_in, const int* in_sizes, int n_in,
                              void* d_out, int out_size, void* d_ws, size_t ws_size,
                              hipStream_t stream)
{
    const float* x    = (const float*)d_in[0];
    const float* xpos = (const float*)d_in[1];
    const float* ypos = (const float*)d_in[2];
    const int* stride = (const int*)d_in[3];
    float* out        = (float*)d_out;

    const int blocks = Bc * Cc * (Hc / ROWS);   // 16*64*16 = 16384
    shift_kernel<<<blocks, 256, 0, stream>>>(x, xpos, ypos, stride, out);
}